// Round 13
// baseline (5501.119 us; speedup 1.0000x reference)
//
#include <hip/hip_runtime.h>

// LSTM: B=64, S=512, I=H=O=1024.  bf16 MFMA, fp32 accum.
// Persistent kernel, 128 blocks x 512 thr (8 waves), 1 block/CU.
// Block owns 8 hidden units -> 32 fused gate cols (c = g*8 + j&7).
// W_h / W_i in MFMA-fragment-linear global order -> LDS linear memcpy ->
// all ds_read_b128 lane-stride-1 (0 bank conflicts, verified R8).
// h-waves 0-3: rows 16w..+15, full K=1024; gates via shfl_xor(8); c in regs.
// x-waves 4-7: x_{t+1} @ W_i one step ahead -> LDS xb (C-fragment lane order).
// R13: h loads are PLAIN CACHED, preceded by one agent-scope ACQUIRE fence
// (waitcnt + buffer_inv of L1+L2) per step after all flags observed. First
// block per XCD fills L2 from LLC; the other 15 hit L2 (~0.2us) instead of
// paying the full LLC RT 16x per step. Cheap now because weights are in LDS
// (R1's fence disaster was the per-step global weight refetch).
// Producer h stores remain sc0 sc1 write-through (LLC-visible before flag).
// Staleness-safe: flags bound all blocks to >= t-1; stores never populate L2;
// fence precedes every h read. Per-step __syncthreads (R11 structure).

typedef __bf16 bfv8 __attribute__((ext_vector_type(8)));
typedef float f32x4 __attribute__((ext_vector_type(4)));
typedef unsigned int u32v4 __attribute__((ext_vector_type(4)));

__device__ __forceinline__ unsigned short f2bf(float x) {
    union { float f; unsigned int u; } v; v.f = x;
    unsigned int r = (v.u + 0x7FFFu + ((v.u >> 16) & 1u)) >> 16;
    return (unsigned short)r;
}

struct SrcPtrs { const float* p[9]; };

// Issue 8 plain cached 16B loads (no wait) at byte offsets O0..O7 from P.
#define ISSUE8C(A, P, O0, O1, O2, O3, O4, O5, O6, O7)                        \
    asm volatile(                                                            \
        "global_load_dwordx4 %0, %8, off offset:" O0 "\n\t"                  \
        "global_load_dwordx4 %1, %8, off offset:" O1 "\n\t"                  \
        "global_load_dwordx4 %2, %8, off offset:" O2 "\n\t"                  \
        "global_load_dwordx4 %3, %8, off offset:" O3 "\n\t"                  \
        "global_load_dwordx4 %4, %8, off offset:" O4 "\n\t"                  \
        "global_load_dwordx4 %5, %8, off offset:" O5 "\n\t"                  \
        "global_load_dwordx4 %6, %8, off offset:" O6 "\n\t"                  \
        "global_load_dwordx4 %7, %8, off offset:" O7                         \
        : "=&v"(A[0]), "=&v"(A[1]), "=&v"(A[2]), "=&v"(A[3]),                \
          "=&v"(A[4]), "=&v"(A[5]), "=&v"(A[6]), "=&v"(A[7])                 \
        : "v"(P)                                                             \
        : "memory")

#define WAIT8(N, A)                                                          \
    do {                                                                     \
        asm volatile("s_waitcnt vmcnt(" N ")"                                \
                     : "+v"(A[0]), "+v"(A[1]), "+v"(A[2]), "+v"(A[3]),       \
                       "+v"(A[4]), "+v"(A[5]), "+v"(A[6]), "+v"(A[7])        \
                     :: "memory");                                           \
        __builtin_amdgcn_sched_barrier(0);                                   \
    } while (0)

// 8 k-steps x 2 N-tiles vs fragment-linear LDS W_h: lane-stride-1, 0 conflicts.
#define CONSUME8(A, IT0)                                                     \
    _Pragma("unroll")                                                        \
    for (int j = 0; j < 8; ++j) {                                            \
        _Pragma("unroll")                                                    \
        for (int n = 0; n < 2; ++n) {                                        \
            const int off = (((((IT0) + j) << 1) | n) << 10) + (lane << 4);  \
            acc[n] = __builtin_amdgcn_mfma_f32_16x16x32_bf16(                \
                A[j], *(const bfv8*)(Lwh + off), acc[n], 0, 0, 0);           \
        }                                                                    \
    }

// ---------------------------------------------------------------------------
__global__ __launch_bounds__(256) void pack_weights(SrcPtrs sp,
                                                    unsigned short* __restrict__ Whp,
                                                    unsigned short* __restrict__ Wip,
                                                    unsigned short* __restrict__ Wy) {
    __shared__ float tile[64][65];
    const int z = blockIdx.z;
    const float* __restrict__ src = sp.p[z];
    const int n0 = blockIdx.x * 64, k0 = blockIdx.y * 64;
    const int tc = threadIdx.x & 63, tq = threadIdx.x >> 6;

    #pragma unroll
    for (int r = 0; r < 16; ++r) {
        const int kk = tq * 16 + r;
        tile[kk][tc] = src[(size_t)(k0 + kk) * 1024 + n0 + tc];
    }
    __syncthreads();
    #pragma unroll
    for (int r = 0; r < 16; ++r) {
        const int nl = tq * 16 + r;
        const int n = n0 + nl;
        const int k = k0 + tc;
        const unsigned short v = f2bf(tile[tc][nl]);
        if (z < 8) {
            const int g = z & 3;
            const int blk = n >> 3;
            const int c = (g << 3) | (n & 7);
            const int lanef = (c & 15) | (((k >> 3) & 3) << 4);
            const size_t off = ((size_t)((((blk << 5) | (k >> 5)) << 1) | (c >> 4)) << 9)
                             + (lanef << 3) + (k & 7);
            (z < 4 ? Whp : Wip)[off] = v;
        } else {
            Wy[(size_t)n * 1024 + k] = v;
        }
    }
}

// ---------------------------------------------------------------------------
__global__ __launch_bounds__(256) void convert_x(const float* __restrict__ x,
                                                 unsigned short* __restrict__ xT) {
    const size_t gid = (size_t)blockIdx.x * 256 + threadIdx.x;
    const int i0 = (int)(gid & 255) * 4;
    const size_t row = gid >> 8;            // dst row = t*64 + b
    const int t = (int)(row >> 6), b = (int)(row & 63);
    const float4 v = *reinterpret_cast<const float4*>(x + (((size_t)b * 512 + t) << 10) + i0);
    ushort4 o;
    o.x = f2bf(v.x); o.y = f2bf(v.y); o.z = f2bf(v.z); o.w = f2bf(v.w);
    *reinterpret_cast<ushort4*>(xT + (row << 10) + i0) = o;
}

// ---------------------------------------------------------------------------
__global__ __launch_bounds__(512) void lstm_seq(const unsigned short* __restrict__ xT,
                                                const unsigned short* __restrict__ Whp,
                                                const unsigned short* __restrict__ Wip,
                                                unsigned short* __restrict__ h0,
                                                unsigned short* __restrict__ h1,
                                                int* __restrict__ flg) {
    __shared__ struct {
        __align__(16) unsigned char wh[65536];   // fragment-linear W_h panel
        __align__(16) unsigned char wi[65536];   // fragment-linear W_i panel
        float xb[2][2][4][256];                  // xpart, C-fragment lane order
        __align__(16) unsigned short hs[64][8];  // h store-coalescing tile
        int sig;                                 // h-wave completion counter
        int Lrdy[4];                             // flag-poll relay epochs
    } L;
    unsigned char* Lwh = L.wh;

    const int tid = threadIdx.x;
    const int w = tid >> 6;           // 0..7
    const int lane = tid & 63;
    const int lr = lane & 15;
    const int kq = lane >> 4;
    const int blk = blockIdx.x;       // 0..127
    const int mw = w & 3;             // batch-row group (rows 16*mw..+15)
    const bool isX = (w >= 4);

    // ---- stage both panels into LDS: pure linear memcpy ----
    #pragma unroll
    for (int s = 0; s < 8; ++s) {
        const int c = s * 512 + tid;          // 16B chunk 0..4095
        *(bfv8*)(L.wh + c * 16) = *(const bfv8*)(Whp + ((size_t)blk << 15) + c * 8);
        *(bfv8*)(L.wi + c * 16) = *(const bfv8*)(Wip + ((size_t)blk << 15) + c * 8);
    }
    if (tid == 0) L.sig = 0;
    if (tid < 4) L.Lrdy[tid] = 0;
    __syncthreads();

    // ---- x-projection worker: xpart(tt) -> L.xb[tt&1] ----
    auto xwork = [&](int tt) {
        const unsigned short* __restrict__ Ax =
            xT + ((size_t)tt << 16) + (size_t)((mw << 4) + lr) * 1024 + kq * 8;
        f32x4 xacc[2] = {};
        #pragma unroll 8
        for (int it = 0; it < 32; ++it) {
            const bfv8 a = *reinterpret_cast<const bfv8*>(Ax + it * 32);
            #pragma unroll
            for (int n = 0; n < 2; ++n) {
                const int off = ((((it << 1) | n) << 10)) + (lane << 4);
                xacc[n] = __builtin_amdgcn_mfma_f32_16x16x32_bf16(
                    a, *(const bfv8*)(L.wi + off), xacc[n], 0, 0, 0);
            }
        }
        #pragma unroll
        for (int n = 0; n < 2; ++n)
            #pragma unroll
            for (int r = 0; r < 4; ++r)
                L.xb[tt & 1][n][r][(mw << 6) + lane] = xacc[n][r];
    };

    if (isX) xwork(0);
    __syncthreads();

    float cst[4] = {0.f, 0.f, 0.f, 0.f};
    const int hoff = ((mw << 4) + lr) * 1024 + kq * 8;

    for (int t = 0; t < 512; ++t) {
        const unsigned short* __restrict__ hin  = (t & 1) ? h1 : h0;
        unsigned short* __restrict__       hout = (t & 1) ? h0 : h1;

        if (!isX) {
            if (t > 0) {
                // wave mw polls flag-group mw (32 flags), relays via LDS stamp
                const int* fp = flg + (((mw << 5) + (lane & 31)) << 5);
                for (;;) {
                    const int f = __hip_atomic_load(fp, __ATOMIC_RELAXED,
                                                    __HIP_MEMORY_SCOPE_AGENT);
                    if (__all(f >= t)) break;
                    __builtin_amdgcn_s_sleep(1);
                }
                __hip_atomic_store(&L.Lrdy[mw], t, __ATOMIC_RELAXED,
                                   __HIP_MEMORY_SCOPE_WORKGROUP);
                // wait ALL groups ready, then one acquire fence (inv L1+L2)
                #pragma unroll
                for (int g = 0; g < 4; ++g)
                    while (__hip_atomic_load(&L.Lrdy[g], __ATOMIC_RELAXED,
                                             __HIP_MEMORY_SCOPE_WORKGROUP) < t) { }
                __builtin_amdgcn_fence(__ATOMIC_ACQUIRE, "agent");
            }

            // depth-2 pipelined CACHED h loads: rows 16mw..+15, K=1024
            const unsigned short* hp = hin + hoff;
            f32x4 acc[2] = {};
            bfv8 a0[8], a1[8];
            ISSUE8C(a0, hp, "0", "64", "128", "192", "256", "320", "384", "448");
            ISSUE8C(a1, hp, "512", "576", "640", "704", "768", "832", "896", "960");
            WAIT8("8", a0);
            CONSUME8(a0, 0);
            ISSUE8C(a0, hp, "1024", "1088", "1152", "1216", "1280", "1344", "1408", "1472");
            WAIT8("8", a1);
            CONSUME8(a1, 8);
            ISSUE8C(a1, hp, "1536", "1600", "1664", "1728", "1792", "1856", "1920", "1984");
            WAIT8("8", a0);
            CONSUME8(a0, 16);
            WAIT8("0", a1);
            CONSUME8(a1, 24);

            // add x-projection partial (C-fragment lane order, conflict-free)
            #pragma unroll
            for (int n = 0; n < 2; ++n)
                #pragma unroll
                for (int r = 0; r < 4; ++r)
                    acc[n][r] += L.xb[t & 1][n][r][(mw << 6) + lane];

            // gate pair-exchange + register-local epilogue
            const bool low = (lr & 8) == 0;
            unsigned short hsv[4];
            #pragma unroll
            for (int r = 0; r < 4; ++r) {
                const float s0 = acc[0][r], s1 = acc[1][r];
                const float x0 = __shfl_xor(s0, 8);
                const float x1 = __shfl_xor(s1, 8);
                const float pi = low ? s0 : x0;
                const float pf = low ? x0 : s0;
                const float po = low ? s1 : x1;
                const float pg = low ? x1 : s1;
                const float ig = 1.f / (1.f + __expf(-pi));
                const float fg = 1.f / (1.f + __expf(-pf));
                const float og = 1.f / (1.f + __expf(-po));
                const float gg = 1.f - 2.f / (__expf(2.f * pg) + 1.f);
                const float cn = fg * cst[r] + ig * gg;
                cst[r] = cn;
                hsv[r] = f2bf(og * (1.f - 2.f / (__expf(2.f * cn) + 1.f)));
            }

            // stage h in LDS (2B writes, own rows), then coalesced 16B stores
            if (low) {
                #pragma unroll
                for (int r = 0; r < 4; ++r)
                    L.hs[(mw << 4) + (kq << 2) + r][lr] = hsv[r];
            }
            asm volatile("s_waitcnt lgkmcnt(0)" ::: "memory");
            __builtin_amdgcn_sched_barrier(0);
            if (lane < 16) {
                const int row = (mw << 4) + lane;
                const u32v4 hv = *reinterpret_cast<const u32v4*>(&L.hs[row][0]);
                asm volatile("global_store_dwordx4 %0, %1, off sc0 sc1"
                             :: "v"(hout + (size_t)row * 1024 + (blk << 3)), "v"(hv)
                             : "memory");
            }
            asm volatile("s_waitcnt vmcnt(0)" ::: "memory");
            // last h-wave to drain posts the block flag (no secondary spin)
            if (lane == 0) {
                const int old = atomicAdd(&L.sig, 1);
                if (old == 4 * t + 3)
                    asm volatile("global_store_dword %0, %1, off sc0 sc1"
                                 :: "v"(flg + (blk << 5)), "v"(t + 1) : "memory");
            }
        } else {
            if (t + 1 < 512) xwork(t + 1);
        }
        __syncthreads();   // xb[(t+1)&1] published; order xb reuse
    }
}

// ---------------------------------------------------------------------------
__global__ __launch_bounds__(256) void final_gemm(const unsigned short* __restrict__ h_in,
                                                  const unsigned short* __restrict__ WyT,
                                                  float* __restrict__ out) {
    const int tid = threadIdx.x;
    const int w = tid >> 6;
    const int lane = tid & 63;
    const int lr = lane & 15;
    const int kq = lane >> 4;
    const int c0 = blockIdx.x * 16;
    const int k0 = w * 256;

    f32x4 acc[4] = {};
    #pragma unroll 2
    for (int it = 0; it < 8; ++it) {
        const int k = k0 + it * 32 + kq * 8;
        const bfv8 bfr = *reinterpret_cast<const bfv8*>(WyT + (size_t)(c0 + lr) * 1024 + k);
        #pragma unroll
        for (int m = 0; m < 4; ++m) {
            const bfv8 a = *reinterpret_cast<const bfv8*>(h_in + (size_t)(m * 16 + lr) * 1024 + k);
            acc[m] = __builtin_amdgcn_mfma_f32_16x16x32_bf16(a, bfr, acc[m], 0, 0, 0);
        }
    }
    __shared__ float red[4][64][17];
    #pragma unroll
    for (int m = 0; m < 4; ++m)
        #pragma unroll
        for (int r = 0; r < 4; ++r)
            red[w][m * 16 + kq * 4 + r][lr] = acc[m][r];
    __syncthreads();
    #pragma unroll
    for (int u = 0; u < 4; ++u) {
        const int item = u * 256 + tid;
        const int b = item >> 4;
        const int jr = item & 15;
        const float s = red[0][b][jr] + red[1][b][jr] + red[2][b][jr] + red[3][b][jr];
        out[b * 1024 + c0 + jr] = s;
    }
}

// ---------------------------------------------------------------------------
extern "C" void kernel_launch(void* const* d_in, const int* in_sizes, int n_in,
                              void* d_out, int out_size, void* d_ws, size_t ws_size,
                              hipStream_t stream) {
    const float* x = (const float*)d_in[0];
    SrcPtrs sp;
    sp.p[0] = (const float*)d_in[1]; // W_hi
    sp.p[1] = (const float*)d_in[3]; // W_hf
    sp.p[2] = (const float*)d_in[5]; // W_ho
    sp.p[3] = (const float*)d_in[7]; // W_hg
    sp.p[4] = (const float*)d_in[2]; // W_ii
    sp.p[5] = (const float*)d_in[4]; // W_if
    sp.p[6] = (const float*)d_in[6]; // W_io
    sp.p[7] = (const float*)d_in[8]; // W_ig
    sp.p[8] = (const float*)d_in[9]; // W_y

    char* ws = (char*)d_ws;
    unsigned short* Whp = (unsigned short*)(ws + 0);          //  8 MB
    unsigned short* Wip = (unsigned short*)(ws + 8388608);    //  8 MB
    unsigned short* Wy  = (unsigned short*)(ws + 16777216);   //  2 MB
    unsigned short* xT  = (unsigned short*)(ws + 18874368);   // 64 MB
    unsigned short* h0  = (unsigned short*)(ws + 86245376);   // 128 KB
    unsigned short* h1  = (unsigned short*)(ws + 86376448);   // 128 KB
    int*            flg = (int*)(ws + 86507520);              // 16 KB (128 x 128B)

    pack_weights<<<dim3(16, 16, 9), 256, 0, stream>>>(sp, Whp, Wip, Wy);
    convert_x<<<32768, 256, 0, stream>>>(x, xT);
    hipMemsetAsync(h0, 0, 64 * 1024 * 2, stream);
    hipMemsetAsync(flg, 0, 128 * 32 * 4, stream);

    lstm_seq<<<128, 512, 0, stream>>>(xT, Whp, Wip, h0, h1, flg);

    final_gemm<<<64, 256, 0, stream>>>(h0, Wy, (float*)d_out);
}

// Round 14
// 3492.169 us; speedup vs baseline: 1.5753x; 1.5753x over previous
//
#include <hip/hip_runtime.h>

// LSTM: B=64, S=512, I=H=O=1024.  bf16 MFMA, fp32 accum.
// R14: producer/consumer CU split. Grid = 256 blocks x 256 thr, 1 block/CU
// (LDS padded to ~99 KB so two blocks never share a CU).
//  - Blocks 0..127 "consumers": 4 h-waves, R10 chain (delegated flag polls,
//    sc0sc1 h loads, LDS W_h fragment-linear, shfl_xor gates, coalesced
//    stores, last-drainer flag). NO x-work, NO __syncthreads in the loop.
//  - Blocks 128..255 "factories": block 128+b computes the x-projection for
//    consumer b, up to 8 steps ahead, into a bf16 ring in ws; paced by the
//    consumer's h-flag (flg >= tt-7). Consumer prefetches its 16B/lane xpart
//    at step start (xflg-guarded); the LLC RT hides under the whole step.
// Fallback: if ws_size < 91 MB, launch the R10-style 512-thr kernel.

typedef __bf16 bfv8 __attribute__((ext_vector_type(8)));
typedef float f32x4 __attribute__((ext_vector_type(4)));
typedef unsigned int u32v4 __attribute__((ext_vector_type(4)));

__device__ __forceinline__ unsigned short f2bf(float x) {
    union { float f; unsigned int u; } v; v.f = x;
    unsigned int r = (v.u + 0x7FFFu + ((v.u >> 16) & 1u)) >> 16;
    return (unsigned short)r;
}
__device__ __forceinline__ float bf2f(unsigned short s) {
    union { unsigned int u; float f; } v; v.u = ((unsigned int)s) << 16;
    return v.f;
}

struct SrcPtrs { const float* p[9]; };

#define ISSUE8(A, P, O0, O1, O2, O3, O4, O5, O6, O7)                         \
    asm volatile(                                                            \
        "global_load_dwordx4 %0, %8, off offset:" O0 " sc0 sc1\n\t"          \
        "global_load_dwordx4 %1, %8, off offset:" O1 " sc0 sc1\n\t"          \
        "global_load_dwordx4 %2, %8, off offset:" O2 " sc0 sc1\n\t"          \
        "global_load_dwordx4 %3, %8, off offset:" O3 " sc0 sc1\n\t"          \
        "global_load_dwordx4 %4, %8, off offset:" O4 " sc0 sc1\n\t"          \
        "global_load_dwordx4 %5, %8, off offset:" O5 " sc0 sc1\n\t"          \
        "global_load_dwordx4 %6, %8, off offset:" O6 " sc0 sc1\n\t"          \
        "global_load_dwordx4 %7, %8, off offset:" O7 " sc0 sc1"              \
        : "=&v"(A[0]), "=&v"(A[1]), "=&v"(A[2]), "=&v"(A[3]),                \
          "=&v"(A[4]), "=&v"(A[5]), "=&v"(A[6]), "=&v"(A[7])                 \
        : "v"(P)                                                             \
        : "memory")

#define WAIT8(N, A)                                                          \
    do {                                                                     \
        asm volatile("s_waitcnt vmcnt(" N ")"                                \
                     : "+v"(A[0]), "+v"(A[1]), "+v"(A[2]), "+v"(A[3]),       \
                       "+v"(A[4]), "+v"(A[5]), "+v"(A[6]), "+v"(A[7])        \
                     :: "memory");                                           \
        __builtin_amdgcn_sched_barrier(0);                                   \
    } while (0)

// 8 k-steps x 2 N-tiles vs fragment-linear LDS panel: lane-stride-1.
#define CONSUME8(A, IT0)                                                     \
    _Pragma("unroll")                                                        \
    for (int j = 0; j < 8; ++j) {                                            \
        _Pragma("unroll")                                                    \
        for (int n = 0; n < 2; ++n) {                                        \
            const int off = (((((IT0) + j) << 1) | n) << 10) + (lane << 4);  \
            acc[n] = __builtin_amdgcn_mfma_f32_16x16x32_bf16(                \
                A[j], *(const bfv8*)(Lw + off), acc[n], 0, 0, 0);            \
        }                                                                    \
    }

// ---------------------------------------------------------------------------
__global__ __launch_bounds__(256) void pack_weights(SrcPtrs sp,
                                                    unsigned short* __restrict__ Whp,
                                                    unsigned short* __restrict__ Wip,
                                                    unsigned short* __restrict__ Wy) {
    __shared__ float tile[64][65];
    const int z = blockIdx.z;
    const float* __restrict__ src = sp.p[z];
    const int n0 = blockIdx.x * 64, k0 = blockIdx.y * 64;
    const int tc = threadIdx.x & 63, tq = threadIdx.x >> 6;

    #pragma unroll
    for (int r = 0; r < 16; ++r) {
        const int kk = tq * 16 + r;
        tile[kk][tc] = src[(size_t)(k0 + kk) * 1024 + n0 + tc];
    }
    __syncthreads();
    #pragma unroll
    for (int r = 0; r < 16; ++r) {
        const int nl = tq * 16 + r;
        const int n = n0 + nl;
        const int k = k0 + tc;
        const unsigned short v = f2bf(tile[tc][nl]);
        if (z < 8) {
            const int g = z & 3;
            const int blk = n >> 3;
            const int c = (g << 3) | (n & 7);
            const int lanef = (c & 15) | (((k >> 3) & 3) << 4);
            const size_t off = ((size_t)((((blk << 5) | (k >> 5)) << 1) | (c >> 4)) << 9)
                             + (lanef << 3) + (k & 7);
            (z < 4 ? Whp : Wip)[off] = v;
        } else {
            Wy[(size_t)n * 1024 + k] = v;
        }
    }
}

// ---------------------------------------------------------------------------
__global__ __launch_bounds__(256) void convert_x(const float* __restrict__ x,
                                                 unsigned short* __restrict__ xT) {
    const size_t gid = (size_t)blockIdx.x * 256 + threadIdx.x;
    const int i0 = (int)(gid & 255) * 4;
    const size_t row = gid >> 8;            // dst row = t*64 + b
    const int t = (int)(row >> 6), b = (int)(row & 63);
    const float4 v = *reinterpret_cast<const float4*>(x + (((size_t)b * 512 + t) << 10) + i0);
    ushort4 o;
    o.x = f2bf(v.x); o.y = f2bf(v.y); o.z = f2bf(v.z); o.w = f2bf(v.w);
    *reinterpret_cast<ushort4*>(xT + (row << 10) + i0) = o;
}

// ---------------------------------------------------------------------------
// R14 unified producer/consumer kernel. 256 blocks x 256 thr.
// ---------------------------------------------------------------------------
__global__ __launch_bounds__(256) void lstm_pc(const unsigned short* __restrict__ xT,
                                               const unsigned short* __restrict__ Whp,
                                               const unsigned short* __restrict__ Wip,
                                               unsigned short* __restrict__ h0,
                                               unsigned short* __restrict__ h1,
                                               int* __restrict__ flg,
                                               int* __restrict__ xflg,
                                               unsigned short* __restrict__ ring) {
    __shared__ struct {
        __align__(16) unsigned char wp[65536];   // fragment-linear W panel
        __align__(16) unsigned char pad[32768];  // force 1 block/CU
        __align__(16) unsigned short hs[64][8];  // h store-coalescing tile
        int sig;
        int Lrdy[4];
    } L;
    unsigned char* Lw = L.wp;

    const int tid = threadIdx.x;
    const int w = tid >> 6;           // 0..3
    const int lane = tid & 63;
    const int lr = lane & 15;
    const int kq = lane >> 4;
    const bool isFactory = (blockIdx.x >= 128);
    const int b = isFactory ? (blockIdx.x - 128) : blockIdx.x;   // pair id

    // ---- stage panel (W_h for consumers, W_i for factories) ----
    {
        const unsigned short* src = (isFactory ? Wip : Whp) + ((size_t)b << 15);
        #pragma unroll
        for (int s = 0; s < 16; ++s) {
            const int c = s * 256 + tid;          // 16B chunk 0..4095
            *(bfv8*)(L.wp + c * 16) = *(const bfv8*)(src + c * 8);
        }
    }
    if (tid == 0) L.sig = 0;
    if (tid < 4) L.Lrdy[tid] = 0;
    __syncthreads();

    if (isFactory) {
        // ============ x-factory: up to 8 steps ahead of consumer ============
        for (int tt = 0; tt < 512; ++tt) {
            if (tt >= 8) {   // ring slot reuse: consumer must have finished tt-8
                const int* cf = flg + (b << 9);
                while (__hip_atomic_load(cf, __ATOMIC_RELAXED, __HIP_MEMORY_SCOPE_AGENT) < tt - 7)
                    __builtin_amdgcn_s_sleep(2);
            }
            const unsigned short* __restrict__ Ax =
                xT + ((size_t)tt << 16) + (size_t)((w << 4) + lr) * 1024 + kq * 8;
            f32x4 xacc[2] = {};
            #pragma unroll 8
            for (int it = 0; it < 32; ++it) {
                const bfv8 a = *reinterpret_cast<const bfv8*>(Ax + it * 32);
                #pragma unroll
                for (int n = 0; n < 2; ++n) {
                    const int off = (((it << 1) | n) << 10) + (lane << 4);
                    xacc[n] = __builtin_amdgcn_mfma_f32_16x16x32_bf16(
                        a, *(const bfv8*)(Lw + off), xacc[n], 0, 0, 0);
                }
            }
            unsigned short vv[8];
            #pragma unroll
            for (int n = 0; n < 2; ++n)
                #pragma unroll
                for (int r = 0; r < 4; ++r)
                    vv[n * 4 + r] = f2bf(xacc[n][r]);
            unsigned short* rp = ring + (((size_t)(b << 3) + (tt & 7)) * 4 + w) * 512 + lane * 8;
            asm volatile("global_store_dwordx4 %0, %1, off sc0 sc1"
                         :: "v"(rp), "v"(*(const u32v4*)vv) : "memory");
            asm volatile("s_waitcnt vmcnt(0)" ::: "memory");
            if (lane == 0) {
                const int old = atomicAdd(&L.sig, 1);
                if (old == 4 * tt + 3)
                    asm volatile("global_store_dword %0, %1, off sc0 sc1"
                                 :: "v"(xflg + (b << 9)), "v"(tt + 1) : "memory");
            }
        }
        return;
    }

    // ================= consumer: h recurrence (4 waves) =================
    float cst[4] = {0.f, 0.f, 0.f, 0.f};
    const int mw = w;
    const int hoff = ((mw << 4) + lr) * 1024 + kq * 8;

    for (int t = 0; t < 512; ++t) {
        const unsigned short* __restrict__ hin  = (t & 1) ? h1 : h0;
        unsigned short* __restrict__       hout = (t & 1) ? h0 : h1;

        // xpart prefetch (factory runs ahead; poll is normally instant)
        const int* xfp = xflg + (b << 9);
        while (__hip_atomic_load(xfp, __ATOMIC_RELAXED, __HIP_MEMORY_SCOPE_AGENT) < t + 1)
            __builtin_amdgcn_s_sleep(1);
        u32v4 xp;
        {
            const unsigned short* rp =
                ring + (((size_t)(b << 3) + (t & 7)) * 4 + mw) * 512 + lane * 8;
            asm volatile("global_load_dwordx4 %0, %1, off sc0 sc1"
                         : "=v"(xp) : "v"(rp) : "memory");
        }

        // wave mw polls flag-group mw (32 flags), relays via LDS stamp
        if (t > 0) {
            const int* fp = flg + (((mw << 5) + (lane & 31)) << 9);
            for (;;) {
                const int f = __hip_atomic_load(fp, __ATOMIC_RELAXED,
                                                __HIP_MEMORY_SCOPE_AGENT);
                if (__all(f >= t)) break;
                __builtin_amdgcn_s_sleep(1);
            }
            __hip_atomic_store(&L.Lrdy[mw], t, __ATOMIC_RELAXED,
                               __HIP_MEMORY_SCOPE_WORKGROUP);
        }
        auto ldswait = [&](int g) {
            if (t == 0) return;
            while (__hip_atomic_load(&L.Lrdy[g], __ATOMIC_RELAXED,
                                     __HIP_MEMORY_SCOPE_WORKGROUP) < t) { }
            asm volatile("" ::: "memory");
        };

        // depth-2 pipelined coherent h loads: rows 16mw..+15, K=1024
        const unsigned short* hp = hin + hoff;
        f32x4 acc[2] = {};
        bfv8 a0[8], a1[8];
        ldswait(0);
        ISSUE8(a0, hp, "0", "64", "128", "192", "256", "320", "384", "448");
        ldswait(1);
        ISSUE8(a1, hp, "512", "576", "640", "704", "768", "832", "896", "960");
        WAIT8("8", a0);
        CONSUME8(a0, 0);
        ldswait(2);
        ISSUE8(a0, hp, "1024", "1088", "1152", "1216", "1280", "1344", "1408", "1472");
        WAIT8("8", a1);
        CONSUME8(a1, 8);
        ldswait(3);
        ISSUE8(a1, hp, "1536", "1600", "1664", "1728", "1792", "1856", "1920", "1984");
        WAIT8("8", a0);
        CONSUME8(a0, 16);
        WAIT8("0", a1);
        CONSUME8(a1, 24);

        // xpart now certainly complete; tie and unpack
        asm volatile("s_waitcnt vmcnt(0)" : "+v"(xp) :: "memory");
        __builtin_amdgcn_sched_barrier(0);
        {
            const unsigned short* xs = (const unsigned short*)&xp;
            #pragma unroll
            for (int n = 0; n < 2; ++n)
                #pragma unroll
                for (int r = 0; r < 4; ++r)
                    acc[n][r] += bf2f(xs[n * 4 + r]);
        }

        // gate pair-exchange + register-local epilogue
        const bool low = (lr & 8) == 0;
        unsigned short hsv[4];
        #pragma unroll
        for (int r = 0; r < 4; ++r) {
            const float s0 = acc[0][r], s1 = acc[1][r];
            const float x0 = __shfl_xor(s0, 8);
            const float x1 = __shfl_xor(s1, 8);
            const float pi = low ? s0 : x0;
            const float pf = low ? x0 : s0;
            const float po = low ? s1 : x1;
            const float pg = low ? x1 : s1;
            const float ig = 1.f / (1.f + __expf(-pi));
            const float fg = 1.f / (1.f + __expf(-pf));
            const float og = 1.f / (1.f + __expf(-po));
            const float gg = 1.f - 2.f / (__expf(2.f * pg) + 1.f);
            const float cn = fg * cst[r] + ig * gg;
            cst[r] = cn;
            hsv[r] = f2bf(og * (1.f - 2.f / (__expf(2.f * cn) + 1.f)));
        }

        // stage h in LDS (wave-private rows), then coalesced 16B stores
        if (low) {
            #pragma unroll
            for (int r = 0; r < 4; ++r)
                L.hs[(mw << 4) + (kq << 2) + r][lr] = hsv[r];
        }
        asm volatile("s_waitcnt lgkmcnt(0)" ::: "memory");
        __builtin_amdgcn_sched_barrier(0);
        if (lane < 16) {
            const int row = (mw << 4) + lane;
            const u32v4 hv = *reinterpret_cast<const u32v4*>(&L.hs[row][0]);
            asm volatile("global_store_dwordx4 %0, %1, off sc0 sc1"
                         :: "v"(hout + (size_t)row * 1024 + (b << 3)), "v"(hv)
                         : "memory");
        }
        asm volatile("s_waitcnt vmcnt(0)" ::: "memory");
        if (lane == 0) {
            const int old = atomicAdd(&L.sig, 1);
            if (old == 4 * t + 3)
                asm volatile("global_store_dword %0, %1, off sc0 sc1"
                             :: "v"(flg + (b << 9)), "v"(t + 1) : "memory");
        }
    }
}

// ---------------------------------------------------------------------------
// Fallback (R10 structure, 128 blocks x 512 thr) — used when ws is small.
// ---------------------------------------------------------------------------
__global__ __launch_bounds__(512) void lstm_fb(const unsigned short* __restrict__ xT,
                                               const unsigned short* __restrict__ Whp,
                                               const unsigned short* __restrict__ Wip,
                                               unsigned short* __restrict__ h0,
                                               unsigned short* __restrict__ h1,
                                               int* __restrict__ flg) {
    __shared__ struct {
        __align__(16) unsigned char wh[65536];
        __align__(16) unsigned char wi[65536];
        float xb[2][2][4][256];
        __align__(16) unsigned short hs[64][8];
        int sig;
    } L;
    unsigned char* Lw = L.wh;

    const int tid = threadIdx.x;
    const int w = tid >> 6;
    const int lane = tid & 63;
    const int lr = lane & 15;
    const int kq = lane >> 4;
    const int blk = blockIdx.x;
    const int mw = w & 3;
    const bool isX = (w >= 4);

    #pragma unroll
    for (int s = 0; s < 8; ++s) {
        const int c = s * 512 + tid;
        *(bfv8*)(L.wh + c * 16) = *(const bfv8*)(Whp + ((size_t)blk << 15) + c * 8);
        *(bfv8*)(L.wi + c * 16) = *(const bfv8*)(Wip + ((size_t)blk << 15) + c * 8);
    }
    if (tid == 0) L.sig = 0;
    __syncthreads();

    auto xwork = [&](int tt) {
        const unsigned short* __restrict__ Ax =
            xT + ((size_t)tt << 16) + (size_t)((mw << 4) + lr) * 1024 + kq * 8;
        f32x4 xacc[2] = {};
        #pragma unroll 8
        for (int it = 0; it < 32; ++it) {
            const bfv8 a = *reinterpret_cast<const bfv8*>(Ax + it * 32);
            #pragma unroll
            for (int n = 0; n < 2; ++n) {
                const int off = (((it << 1) | n) << 10) + (lane << 4);
                xacc[n] = __builtin_amdgcn_mfma_f32_16x16x32_bf16(
                    a, *(const bfv8*)(L.wi + off), xacc[n], 0, 0, 0);
            }
        }
        #pragma unroll
        for (int n = 0; n < 2; ++n)
            #pragma unroll
            for (int r = 0; r < 4; ++r)
                L.xb[tt & 1][n][r][(mw << 6) + lane] = xacc[n][r];
    };

    if (isX) xwork(0);
    __syncthreads();

    float cst[4] = {0.f, 0.f, 0.f, 0.f};
    const int hoff = ((mw << 4) + lr) * 1024 + kq * 8;

    for (int t = 0; t < 512; ++t) {
        const unsigned short* __restrict__ hin  = (t & 1) ? h1 : h0;
        unsigned short* __restrict__       hout = (t & 1) ? h0 : h1;

        if (!isX) {
            auto poll32 = [&](int g) {
                if (t == 0) return;
                const int* fp = flg + (((g << 5) + (lane & 31)) << 9);
                for (;;) {
                    const int f = __hip_atomic_load(fp, __ATOMIC_RELAXED,
                                                    __HIP_MEMORY_SCOPE_AGENT);
                    if (__all(f >= t)) break;
                    __builtin_amdgcn_s_sleep(1);
                }
            };
            const unsigned short* hp = hin + hoff;
            f32x4 acc[2] = {};
            bfv8 a0[8], a1[8];
            poll32(0);
            ISSUE8(a0, hp, "0", "64", "128", "192", "256", "320", "384", "448");
            poll32(1);
            ISSUE8(a1, hp, "512", "576", "640", "704", "768", "832", "896", "960");
            WAIT8("8", a0);
            CONSUME8(a0, 0);
            poll32(2);
            ISSUE8(a0, hp, "1024", "1088", "1152", "1216", "1280", "1344", "1408", "1472");
            WAIT8("8", a1);
            CONSUME8(a1, 8);
            poll32(3);
            ISSUE8(a1, hp, "1536", "1600", "1664", "1728", "1792", "1856", "1920", "1984");
            WAIT8("8", a0);
            CONSUME8(a0, 16);
            WAIT8("0", a1);
            CONSUME8(a1, 24);

            #pragma unroll
            for (int n = 0; n < 2; ++n)
                #pragma unroll
                for (int r = 0; r < 4; ++r)
                    acc[n][r] += L.xb[t & 1][n][r][(mw << 6) + lane];

            const bool low = (lr & 8) == 0;
            unsigned short hsv[4];
            #pragma unroll
            for (int r = 0; r < 4; ++r) {
                const float s0 = acc[0][r], s1 = acc[1][r];
                const float x0 = __shfl_xor(s0, 8);
                const float x1 = __shfl_xor(s1, 8);
                const float pi = low ? s0 : x0;
                const float pf = low ? x0 : s0;
                const float po = low ? s1 : x1;
                const float pg = low ? x1 : s1;
                const float ig = 1.f / (1.f + __expf(-pi));
                const float fg = 1.f / (1.f + __expf(-pf));
                const float og = 1.f / (1.f + __expf(-po));
                const float gg = 1.f - 2.f / (__expf(2.f * pg) + 1.f);
                const float cn = fg * cst[r] + ig * gg;
                cst[r] = cn;
                hsv[r] = f2bf(og * (1.f - 2.f / (__expf(2.f * cn) + 1.f)));
            }
            if (low) {
                #pragma unroll
                for (int r = 0; r < 4; ++r)
                    L.hs[(mw << 4) + (kq << 2) + r][lr] = hsv[r];
            }
            asm volatile("s_waitcnt lgkmcnt(0)" ::: "memory");
            __builtin_amdgcn_sched_barrier(0);
            if (lane < 16) {
                const int row = (mw << 4) + lane;
                const u32v4 hv = *reinterpret_cast<const u32v4*>(&L.hs[row][0]);
                asm volatile("global_store_dwordx4 %0, %1, off sc0 sc1"
                             :: "v"(hout + (size_t)row * 1024 + (blk << 3)), "v"(hv)
                             : "memory");
            }
            asm volatile("s_waitcnt vmcnt(0)" ::: "memory");
            if (lane == 0) {
                const int old = atomicAdd(&L.sig, 1);
                if (old == 4 * t + 3)
                    asm volatile("global_store_dword %0, %1, off sc0 sc1"
                                 :: "v"(flg + (blk << 9)), "v"(t + 1) : "memory");
            }
        } else {
            if (t + 1 < 512) xwork(t + 1);
        }
        __syncthreads();
    }
}

// ---------------------------------------------------------------------------
__global__ __launch_bounds__(256) void final_gemm(const unsigned short* __restrict__ h_in,
                                                  const unsigned short* __restrict__ WyT,
                                                  float* __restrict__ out) {
    const int tid = threadIdx.x;
    const int w = tid >> 6;
    const int lane = tid & 63;
    const int lr = lane & 15;
    const int kq = lane >> 4;
    const int c0 = blockIdx.x * 16;
    const int k0 = w * 256;

    f32x4 acc[4] = {};
    #pragma unroll 2
    for (int it = 0; it < 8; ++it) {
        const int k = k0 + it * 32 + kq * 8;
        const bfv8 bfr = *reinterpret_cast<const bfv8*>(WyT + (size_t)(c0 + lr) * 1024 + k);
        #pragma unroll
        for (int m = 0; m < 4; ++m) {
            const bfv8 a = *reinterpret_cast<const bfv8*>(h_in + (size_t)(m * 16 + lr) * 1024 + k);
            acc[m] = __builtin_amdgcn_mfma_f32_16x16x32_bf16(a, bfr, acc[m], 0, 0, 0);
        }
    }
    __shared__ float red[4][64][17];
    #pragma unroll
    for (int m = 0; m < 4; ++m)
        #pragma unroll
        for (int r = 0; r < 4; ++r)
            red[w][m * 16 + kq * 4 + r][lr] = acc[m][r];
    __syncthreads();
    #pragma unroll
    for (int u = 0; u < 4; ++u) {
        const int item = u * 256 + tid;
        const int b = item >> 4;
        const int jr = item & 15;
        const float s = red[0][b][jr] + red[1][b][jr] + red[2][b][jr] + red[3][b][jr];
        out[b * 1024 + c0 + jr] = s;
    }
}

// ---------------------------------------------------------------------------
extern "C" void kernel_launch(void* const* d_in, const int* in_sizes, int n_in,
                              void* d_out, int out_size, void* d_ws, size_t ws_size,
                              hipStream_t stream) {
    const float* x = (const float*)d_in[0];
    SrcPtrs sp;
    sp.p[0] = (const float*)d_in[1]; // W_hi
    sp.p[1] = (const float*)d_in[3]; // W_hf
    sp.p[2] = (const float*)d_in[5]; // W_ho
    sp.p[3] = (const float*)d_in[7]; // W_hg
    sp.p[4] = (const float*)d_in[2]; // W_ii
    sp.p[5] = (const float*)d_in[4]; // W_if
    sp.p[6] = (const float*)d_in[6]; // W_io
    sp.p[7] = (const float*)d_in[8]; // W_ig
    sp.p[8] = (const float*)d_in[9]; // W_y

    char* ws = (char*)d_ws;
    unsigned short* Whp  = (unsigned short*)(ws + 0);          //  8 MB
    unsigned short* Wip  = (unsigned short*)(ws + 8388608);    //  8 MB
    unsigned short* Wy   = (unsigned short*)(ws + 16777216);   //  2 MB
    unsigned short* xT   = (unsigned short*)(ws + 18874368);   // 64 MB -> 85983232
    unsigned short* h0   = (unsigned short*)(ws + 85983232);   // 128 KB
    unsigned short* h1   = (unsigned short*)(ws + 86114304);   // 128 KB
    int*            flg  = (int*)(ws + 86245376);              // 256 KB (128 x 2KB)
    int*            xflg = (int*)(ws + 86507520);              // 256 KB
    unsigned short* ring = (unsigned short*)(ws + 86769664);   // 4 MB -> 90963968

    const bool split = ws_size >= 90963968ull;

    pack_weights<<<dim3(16, 16, 9), 256, 0, stream>>>(sp, Whp, Wip, Wy);
    convert_x<<<32768, 256, 0, stream>>>(x, xT);
    hipMemsetAsync(h0, 0, 131072, stream);
    hipMemsetAsync(flg, 0, 262144, stream);

    if (split) {
        hipMemsetAsync(xflg, 0, 262144, stream);
        lstm_pc<<<256, 256, 0, stream>>>(xT, Whp, Wip, h0, h1, flg, xflg, ring);
    } else {
        lstm_fb<<<128, 512, 0, stream>>>(xT, Whp, Wip, h0, h1, flg);
    }

    final_gemm<<<64, 256, 0, stream>>>(h0, Wy, (float*)d_out);
}